// Round 6
// baseline (638.820 us; speedup 1.0000x reference)
//
#include <hip/hip_runtime.h>
#include <hip/hip_bf16.h>
#include <math.h>

typedef float f32x4 __attribute__((ext_vector_type(4)));
typedef short s16x8 __attribute__((ext_vector_type(8)));

#define L2E 1.4426950408889634f
#define C2L2E 2.885390081777927f  // 2*log2(e)

__device__ __forceinline__ unsigned pack_bf16x2_rne(float a, float b) {
  __hip_bfloat162 t = __float22bfloat162_rn(float2{a, b});
  unsigned r;
  __builtin_memcpy(&r, &t, 4);
  return r;  // low 16 = a, high 16 = b
}

// ---------------- K0: W-hi (swizzled W^T, for LDS stage), W-lo (frag-major,
// stays in global/L1), S zero ------------------------------------------------
__global__ void k0_prep(const float* __restrict__ W,
                        unsigned short* __restrict__ gWhi,
                        unsigned short* __restrict__ gBlo,
                        float* __restrict__ S) {
  int bid = blockIdx.x;
  if (bid < 64) {  // hi: addr = e*128 + (d ^ ((e&7)<<3)), RNE
    int t = bid * 256 + threadIdx.x;
    int d = t >> 7, e = t & 127;
    float w = W[d * 128 + e];
    unsigned u = __float_as_uint(w);
    unsigned hb = (u + 0x7fffu + ((u >> 16) & 1u)) >> 16;
    gWhi[e * 128 + (d ^ ((e & 7) << 3))] = (unsigned short)hb;
  } else if (bid < 128) {  // lo: frag-major t = fs*512 + lane*8 + q
    int t = (bid - 64) * 256 + threadIdx.x;
    int q = t & 7, lane = (t >> 3) & 63, fs = t >> 9;
    int kstep = fs & 3, et = fs >> 2;
    int e = (lane & 15) + 16 * et;
    int k = 32 * kstep + 8 * (lane >> 4) + q;
    float w = W[k * 128 + e];
    unsigned u = __float_as_uint(w);
    unsigned hb = (u + 0x7fffu + ((u >> 16) & 1u)) >> 16;  // same hi as above
    float r = w - __uint_as_float(hb << 16);
    unsigned ul = __float_as_uint(r);
    gBlo[t] = (unsigned short)((ul + 0x7fffu + ((ul >> 16) & 1u)) >> 16);
  } else {
    S[(bid - 128) * 256 + threadIdx.x] = 0.f;
  }
}

// ---------------- KA: E=exp(logit) + row sums, triangular + mirror ----------
// 16i x 16j tile, 4 waves; each wave: 4 i's in TWO passes of 2 (acc=64 regs).
// B-hi from LDS, B-lo from global (32 KB, L1-resident).
__global__ __launch_bounds__(256, 3) void kA_logits(
    const float* __restrict__ x, const unsigned short* __restrict__ gWhi,
    const unsigned short* __restrict__ gBlo, const float* __restrict__ apb,
    const float* __restrict__ av, float* __restrict__ Lg,
    float* __restrict__ S) {
  __shared__ __align__(16) unsigned short sWhi[16384];  // 32 KB
  __shared__ __align__(16) float sXj[16 * 132];         // 8448 B
  __shared__ float sRow[16][4];
  __shared__ float sMir[16];

  int tt = blockIdx.x, ti = 0;
  while (tt >= 16 - ti) { tt -= 16 - ti; ++ti; }
  const int tj = ti + tt;
  const int b = blockIdx.y;
  const int i0 = ti * 16, j0 = tj * 16;
  const int tid = threadIdx.x;

  {  // stage W-hi (pre-swizzled copy) + x_j rows
    const uint4* shi = (const uint4*)gWhi;
    uint4* dhi = (uint4*)sWhi;
#pragma unroll
    for (int r = 0; r < 8; ++r) dhi[tid + 256 * r] = shi[tid + 256 * r];
    const float4* xsrc = (const float4*)(x + ((size_t)(b * 256 + j0)) * 128);
#pragma unroll
    for (int r = 0; r < 2; ++r) {
      int v = tid + 256 * r;
      *(float4*)&sXj[(v >> 5) * 132 + (v & 31) * 4] = xsrc[v];
    }
  }
  __syncthreads();

  const int lane = tid & 63;
  const int w = tid >> 6;
  const int quad = lane >> 4;
  const int col = lane & 15;
  const int swz = (col & 7) << 3;

  float bias[8], vw[8];
#pragma unroll
  for (int et = 0; et < 8; ++et) {
    bias[et] = apb[col + 16 * et];
    vw[et] = av[col + 16 * et];
  }

  const float* xib = x + ((size_t)(b * 256 + i0 + 4 * w)) * 128;
  const unsigned short* gBlL = gBlo + lane * 8;

  for (int p = 0; p < 2; ++p) {
    f32x4 acc[2][8];
#pragma unroll
    for (int et = 0; et < 8; ++et) {
      acc[0][et] = (f32x4){bias[et], bias[et], bias[et], bias[et]};
      acc[1][et] = (f32x4){bias[et], bias[et], bias[et], bias[et]};
    }

#pragma unroll
    for (int kstep = 0; kstep < 4; ++kstep) {
      const int k0 = kstep * 32 + quad * 8;
      float4 xj0 = *(const float4*)&sXj[col * 132 + k0];
      float4 xj1 = *(const float4*)&sXj[col * 132 + k0 + 4];
      s16x8 Ah[2], Al[2];
#pragma unroll
      for (int mt = 0; mt < 2; ++mt) {
        const float* xip = xib + (2 * p + mt) * 128 + k0;
        float4 xi0 = *(const float4*)xip;
        float4 xi1 = *(const float4*)(xip + 4);
        float pv[8];
        pv[0] = xi0.x * xj0.x; pv[1] = xi0.y * xj0.y;
        pv[2] = xi0.z * xj0.z; pv[3] = xi0.w * xj0.w;
        pv[4] = xi1.x * xj1.x; pv[5] = xi1.y * xj1.y;
        pv[6] = xi1.z * xj1.z; pv[7] = xi1.w * xj1.w;
        uint4 hp, lp;
        unsigned* hq = (unsigned*)&hp;
        unsigned* lq = (unsigned*)&lp;
#pragma unroll
        for (int pp = 0; pp < 4; ++pp) {
          float a = pv[2 * pp], c = pv[2 * pp + 1];
          unsigned hv = pack_bf16x2_rne(a, c);
          float h0 = __uint_as_float(hv << 16);
          float h1 = __uint_as_float(hv & 0xffff0000u);
          lq[pp] = pack_bf16x2_rne(a - h0, c - h1);
          hq[pp] = hv;
        }
        Ah[mt] = *(s16x8*)&hp;
        Al[mt] = *(s16x8*)&lp;
      }
#pragma unroll
      for (int et = 0; et < 8; ++et) {
        s16x8 bh = *(const s16x8*)&sWhi[(col + 16 * et) * 128 + (k0 ^ swz)];
        s16x8 bl = *(const s16x8*)(gBlL + (et * 4 + kstep) * 512);
#pragma unroll
        for (int mt = 0; mt < 2; ++mt) {
          acc[mt][et] = __builtin_amdgcn_mfma_f32_16x16x32_bf16(Ah[mt], bh, acc[mt][et], 0, 0, 0);
          acc[mt][et] = __builtin_amdgcn_mfma_f32_16x16x32_bf16(Al[mt], bh, acc[mt][et], 0, 0, 0);
          acc[mt][et] = __builtin_amdgcn_mfma_f32_16x16x32_bf16(Ah[mt], bl, acc[mt][et], 0, 0, 0);
        }
      }
    }

    // epilogue for this pass's 2 i's
    float E[2];
#pragma unroll
    for (int mt = 0; mt < 2; ++mt) {
      float ls[4] = {0.f, 0.f, 0.f, 0.f};
#pragma unroll
      for (int et = 0; et < 8; ++et) {
#pragma unroll
        for (int r = 0; r < 4; ++r) {
          float e2 = __builtin_amdgcn_exp2f(acc[mt][et][r] * C2L2E);
          float t = 1.0f - 2.0f * __builtin_amdgcn_rcpf(e2 + 1.0f);
          ls[r] += t * vw[et];
        }
      }
#pragma unroll
      for (int m = 1; m < 16; m <<= 1) {
        ls[0] += __shfl_xor(ls[0], m);
        ls[1] += __shfl_xor(ls[1], m);
        ls[2] += __shfl_xor(ls[2], m);
        ls[3] += __shfl_xor(ls[3], m);
      }
      float fl = (col == 0) ? ls[0] : (col == 1) ? ls[1] : (col == 2) ? ls[2] : ls[3];
      E[mt] = __builtin_amdgcn_exp2f(fl * L2E);
    }

    if (col < 4) {
      const int j = j0 + quad * 4 + col;
      float2 val = {E[0], E[1]};
      *(float2*)&Lg[((size_t)(b * 256 + j)) * 256 + i0 + 4 * w + 2 * p] = val;
      float rs = E[0] + E[1];
      if (p == 0) sRow[quad * 4 + col][w] = rs;
      else sRow[quad * 4 + col][w] += rs;
      if (ti != tj) {
        Lg[((size_t)(b * 256 + i0 + 4 * w + 2 * p)) * 256 + j] = E[0];
        Lg[((size_t)(b * 256 + i0 + 4 * w + 2 * p + 1)) * 256 + j] = E[1];
      }
    }
    if (ti != tj) {
#pragma unroll
      for (int mt = 0; mt < 2; ++mt) {
        float v = (col < 4) ? E[mt] : 0.f;
#pragma unroll
        for (int m = 1; m < 64; m <<= 1) v += __shfl_xor(v, m);
        if (lane == 0) sMir[4 * w + 2 * p + mt] = v;
      }
    }
  }
  __syncthreads();
  if (tid < 16) {
    atomicAdd(&S[b * 256 + j0 + tid],
              sRow[tid][0] + sRow[tid][1] + sRow[tid][2] + sRow[tid][3]);
    if (ti != tj) atomicAdd(&S[b * 256 + i0 + tid], sMir[tid]);
  }
}

// ---------------- KB: agg (att=E/S, symmetric row reads) + h (fp64) + scores
__global__ void kB_aggh(const float* __restrict__ Lg, const float* __restrict__ S,
                        const float* __restrict__ x,
                        const float* __restrict__ pwa, const float* __restrict__ pwoa,
                        const float* __restrict__ pwab, const float* __restrict__ pwob,
                        const float* __restrict__ gam, const float* __restrict__ bet,
                        const float* __restrict__ mea, const float* __restrict__ varr,
                        const float* __restrict__ plw, const float* __restrict__ plb,
                        float* __restrict__ h, float* __restrict__ scores) {
  const int b = blockIdx.y, i0 = blockIdx.x * 8;
  const int tid = threadIdx.x;
  const int il = tid >> 5, dl = tid & 31;  // 8 i x 32 d-chunks
  __shared__ float sInv[256];
  __shared__ float satt[16][9];
  __shared__ float sxj[2048];
  __shared__ float sa[1024];
  __shared__ float sxi[1024];
  __shared__ double sScD[8][32];

  sInv[tid] = 1.0f / S[b * 256 + tid];
  ((float4*)sxi)[tid] = ((const float4*)(x + ((size_t)(b * 256 + i0)) * 128))[tid];

  float acc[4] = {0.f, 0.f, 0.f, 0.f};
  for (int jj = 0; jj < 256; jj += 16) {
    __syncthreads();
    if (tid < 128) {
      int ir = tid >> 4, jc = tid & 15;  // E(j,i)=E(i,j): coalesced row read
      satt[jc][ir] = Lg[((size_t)(b * 256 + i0 + ir)) * 256 + jj + jc] *
                     sInv[jj + jc];
    }
    const float4* xsrc = (const float4*)(x + ((size_t)(b * 256 + jj)) * 128);
    ((float4*)sxj)[tid] = xsrc[tid];
    ((float4*)sxj)[tid + 256] = xsrc[tid + 256];
    __syncthreads();
#pragma unroll
    for (int jl = 0; jl < 16; ++jl) {
      float a = satt[jl][il];
      float4 xv = *(const float4*)&sxj[jl * 128 + dl * 4];
      acc[0] += a * xv.x; acc[1] += a * xv.y;
      acc[2] += a * xv.z; acc[3] += a * xv.w;
    }
  }
  __syncthreads();
  *(float4*)&sa[il * 128 + dl * 4] = *(float4*)acc;
  __syncthreads();

  double z[4] = {0, 0, 0, 0};
  for (int k = 0; k < 128; ++k) {
    double a = (double)sa[il * 128 + k];
    float4 wv = *(const float4*)(pwa + k * 128 + dl * 4);
    z[0] += a * (double)wv.x; z[1] += a * (double)wv.y;
    z[2] += a * (double)wv.z; z[3] += a * (double)wv.w;
  }
  for (int k = 0; k < 128; ++k) {
    double a = (double)sxi[il * 128 + k];
    float4 wv = *(const float4*)(pwoa + k * 128 + dl * 4);
    z[0] += a * (double)wv.x; z[1] += a * (double)wv.y;
    z[2] += a * (double)wv.z; z[3] += a * (double)wv.w;
  }
  float o[4];
#pragma unroll
  for (int q = 0; q < 4; ++q) {
    int d = dl * 4 + q;
    double hv = z[q] + (double)pwab[d] + (double)pwob[d];
    double bn = (hv - (double)mea[d]) * (1.0 / sqrt((double)varr[d] + 1e-5)) *
                    (double)gam[d] +
                (double)bet[d];
    float bf = (float)bn;
    o[q] = bf > 0.f ? 1.0507009873554805f * bf
                    : 1.7580993408473766f *
                          (__builtin_amdgcn_exp2f(bf * L2E) - 1.0f);
  }
  *(float4*)(h + ((size_t)(b * 256 + i0 + il)) * 128 + dl * 4) = *(float4*)o;

  sScD[il][dl] = (double)o[0] * (double)plw[dl * 4] +
                 (double)o[1] * (double)plw[dl * 4 + 1] +
                 (double)o[2] * (double)plw[dl * 4 + 2] +
                 (double)o[3] * (double)plw[dl * 4 + 3];
  __syncthreads();
  if (tid < 8) {
    double zz = (double)plb[0];
    for (int c = 0; c < 32; ++c) zz += sScD[tid][c];
    scores[b * 256 + i0 + tid] = (float)(1.0 / (1.0 + exp(-zz)));
  }
}

// ---------------- KC: stable top-128 rank + gather h*score ------------------
__global__ __launch_bounds__(1024) void kC_topk(const float* __restrict__ h,
                                                const float* __restrict__ scores,
                                                float* __restrict__ out) {
  const int b = blockIdx.x, tid = threadIdx.x;
  const int t = tid >> 2, c = tid & 3;
  __shared__ float sc[256];
  __shared__ int ipart[256][4];
  __shared__ int sel[128];

  if (c == 0) sc[t] = scores[b * 256 + t];
  __syncthreads();
  {
    const float st = sc[t];
    int r = 0;
    for (int m = c * 64; m < c * 64 + 64; ++m) {
      float sm = sc[m];
      r += (sm > st) || (sm == st && m < t);  // stable descending
    }
    ipart[t][c] = r;
  }
  __syncthreads();
  if (c == 0) {
    int rank = ipart[t][0] + ipart[t][1] + ipart[t][2] + ipart[t][3];
    if (rank < 128) sel[rank] = t;
  }
  __syncthreads();
  const float4* h4 = (const float4*)(h + (size_t)b * 256 * 128);
  float4* o4 = (float4*)(out + (size_t)b * 128 * 128);
#pragma unroll
  for (int r = 0; r < 4; ++r) {
    int v = tid + 1024 * r;
    int row = v >> 5, q = v & 31;
    int src = sel[row];
    float ss = sc[src];
    float4 hv = h4[src * 32 + q];
    float4 ov;
    ov.x = hv.x * ss; ov.y = hv.y * ss; ov.z = hv.z * ss; ov.w = hv.w * ss;
    o4[row * 32 + q] = ov;
  }
}

extern "C" void kernel_launch(void* const* d_in, const int* in_sizes, int n_in,
                              void* d_out, int out_size, void* d_ws, size_t ws_size,
                              hipStream_t stream) {
  const float* x    = (const float*)d_in[0];
  const float* apw  = (const float*)d_in[1];
  const float* apb  = (const float*)d_in[2];
  const float* av   = (const float*)d_in[3];
  const float* pwa  = (const float*)d_in[4];
  const float* pwab = (const float*)d_in[5];
  const float* pwoa = (const float*)d_in[6];
  const float* pwob = (const float*)d_in[7];
  const float* gam  = (const float*)d_in[8];
  const float* bet  = (const float*)d_in[9];
  const float* mea  = (const float*)d_in[10];
  const float* varr = (const float*)d_in[11];
  const float* plw  = (const float*)d_in[12];
  const float* plb  = (const float*)d_in[13];
  float* out = (float*)d_out;

  // ws: gWhi 32K | gBlo 32K | S 16K | Lg 4M | h 2M | scores 16K
  unsigned short* gWhi = (unsigned short*)d_ws;
  unsigned short* gBlo = gWhi + 16384;
  float* S  = (float*)((char*)d_ws + 65536);
  float* Lg = (float*)((char*)d_ws + 81920);
  float* hb = Lg + (size_t)16 * 256 * 256;
  float* sco = hb + (size_t)16 * 256 * 128;

  k0_prep<<<144, 256, 0, stream>>>(apw, gWhi, gBlo, S);
  kA_logits<<<dim3(136, 16), 256, 0, stream>>>(x, gWhi, gBlo, apb, av, Lg, S);
  kB_aggh<<<dim3(32, 16), 256, 0, stream>>>(Lg, S, x, pwa, pwoa, pwab, pwob,
                                            gam, bet, mea, varr, plw, plb, hb, sco);
  kC_topk<<<16, 1024, 0, stream>>>(hb, sco, out);
}

// Round 7
// 188.604 us; speedup vs baseline: 3.3871x; 3.3871x over previous
//
#include <hip/hip_runtime.h>
#include <hip/hip_bf16.h>
#include <math.h>

typedef float f32x4 __attribute__((ext_vector_type(4)));
typedef short s16x8 __attribute__((ext_vector_type(8)));

#define L2E 1.4426950408889634f
#define C2L2E 2.885390081777927f  // 2*log2(e)

__device__ __forceinline__ unsigned pack_bf16x2_rne(float a, float b) {
  __hip_bfloat162 t = __float22bfloat162_rn(float2{a, b});
  unsigned r;
  __builtin_memcpy(&r, &t, 4);
  return r;  // low 16 = a, high 16 = b
}

// ---------------- K0: W-hi (swizzled W^T -> LDS stage), W-lo (frag-major,
// global/L1-resident), S zero ------------------------------------------------
__global__ void k0_prep(const float* __restrict__ W,
                        unsigned short* __restrict__ gWhi,
                        unsigned short* __restrict__ gBlo,
                        float* __restrict__ S) {
  int bid = blockIdx.x;
  if (bid < 64) {  // hi: addr = e*128 + (d ^ ((e&7)<<3)), RNE
    int t = bid * 256 + threadIdx.x;
    int d = t >> 7, e = t & 127;
    float w = W[d * 128 + e];
    unsigned u = __float_as_uint(w);
    unsigned hb = (u + 0x7fffu + ((u >> 16) & 1u)) >> 16;
    gWhi[e * 128 + (d ^ ((e & 7) << 3))] = (unsigned short)hb;
  } else if (bid < 128) {  // lo: frag-major t = fs*512 + lane*8 + q
    int t = (bid - 64) * 256 + threadIdx.x;
    int q = t & 7, lane = (t >> 3) & 63, fs = t >> 9;
    int kstep = fs & 3, et = fs >> 2;
    int e = (lane & 15) + 16 * et;
    int k = 32 * kstep + 8 * (lane >> 4) + q;
    float w = W[k * 128 + e];
    unsigned u = __float_as_uint(w);
    unsigned hb = (u + 0x7fffu + ((u >> 16) & 1u)) >> 16;  // same hi as above
    float r = w - __uint_as_float(hb << 16);
    unsigned ul = __float_as_uint(r);
    gBlo[t] = (unsigned short)((ul + 0x7fffu + ((ul >> 16) & 1u)) >> 16);
  } else {
    S[(bid - 128) * 256 + threadIdx.x] = 0.f;
  }
}

// ---------------- KA: E=exp(logit) + row sums, triangular half-tiles --------
// block = 16 j x 8 i (half of a 16x16 tile), 4 waves, mt=2 -> acc = 64 regs.
// grid (136 tiles, 2 halves, 16 b). B-hi LDS, B-lo global/L1. Single pass.
__global__ __launch_bounds__(256, 3) void kA_logits(
    const float* __restrict__ x, const unsigned short* __restrict__ gWhi,
    const unsigned short* __restrict__ gBlo, const float* __restrict__ apb,
    const float* __restrict__ av, float* __restrict__ Lg,
    float* __restrict__ S) {
  __shared__ __align__(16) unsigned short sWhi[16384];  // 32 KB
  __shared__ __align__(16) float sXj[16 * 132];         // 8448 B
  __shared__ float sRow[16][4];
  __shared__ float sMir[8];

  int tt = blockIdx.x, ti = 0;
  while (tt >= 16 - ti) { tt -= 16 - ti; ++ti; }
  const int tj = ti + tt;
  const int b = blockIdx.z;
  const int i0 = ti * 16 + blockIdx.y * 8, j0 = tj * 16;
  const int tid = threadIdx.x;

  {  // stage W-hi (pre-swizzled copy) + x_j rows
    const uint4* shi = (const uint4*)gWhi;
    uint4* dhi = (uint4*)sWhi;
#pragma unroll
    for (int r = 0; r < 8; ++r) dhi[tid + 256 * r] = shi[tid + 256 * r];
    const float4* xsrc = (const float4*)(x + ((size_t)(b * 256 + j0)) * 128);
#pragma unroll
    for (int r = 0; r < 2; ++r) {
      int v = tid + 256 * r;
      *(float4*)&sXj[(v >> 5) * 132 + (v & 31) * 4] = xsrc[v];
    }
  }
  __syncthreads();

  const int lane = tid & 63;
  const int w = tid >> 6;
  const int quad = lane >> 4;
  const int col = lane & 15;
  const int swz = (col & 7) << 3;

  f32x4 acc[2][8];
#pragma unroll
  for (int et = 0; et < 8; ++et) {
    float bi = apb[col + 16 * et];  // transient: dead after init
    acc[0][et] = (f32x4){bi, bi, bi, bi};
    acc[1][et] = (f32x4){bi, bi, bi, bi};
  }

  const float* xib = x + ((size_t)(b * 256 + i0 + 2 * w)) * 128;
  const unsigned short* gBlL = gBlo + lane * 8;

#pragma unroll
  for (int kstep = 0; kstep < 4; ++kstep) {
    const int k0 = kstep * 32 + quad * 8;
    float4 xj0 = *(const float4*)&sXj[col * 132 + k0];
    float4 xj1 = *(const float4*)&sXj[col * 132 + k0 + 4];
    s16x8 Ah[2], Al[2];
#pragma unroll
    for (int mt = 0; mt < 2; ++mt) {
      const float* xip = xib + mt * 128 + k0;
      float4 xi0 = *(const float4*)xip;
      float4 xi1 = *(const float4*)(xip + 4);
      float pv[8];
      pv[0] = xi0.x * xj0.x; pv[1] = xi0.y * xj0.y;
      pv[2] = xi0.z * xj0.z; pv[3] = xi0.w * xj0.w;
      pv[4] = xi1.x * xj1.x; pv[5] = xi1.y * xj1.y;
      pv[6] = xi1.z * xj1.z; pv[7] = xi1.w * xj1.w;
      uint4 hp, lp;
      unsigned* hq = (unsigned*)&hp;
      unsigned* lq = (unsigned*)&lp;
#pragma unroll
      for (int pp = 0; pp < 4; ++pp) {
        float a = pv[2 * pp], c = pv[2 * pp + 1];
        unsigned hv = pack_bf16x2_rne(a, c);
        float h0 = __uint_as_float(hv << 16);
        float h1 = __uint_as_float(hv & 0xffff0000u);
        lq[pp] = pack_bf16x2_rne(a - h0, c - h1);
        hq[pp] = hv;
      }
      Ah[mt] = *(s16x8*)&hp;
      Al[mt] = *(s16x8*)&lp;
    }
#pragma unroll
    for (int et = 0; et < 8; ++et) {
      s16x8 bh = *(const s16x8*)&sWhi[(col + 16 * et) * 128 + (k0 ^ swz)];
      s16x8 bl = *(const s16x8*)(gBlL + (et * 4 + kstep) * 512);
#pragma unroll
      for (int mt = 0; mt < 2; ++mt) {
        acc[mt][et] = __builtin_amdgcn_mfma_f32_16x16x32_bf16(Ah[mt], bh, acc[mt][et], 0, 0, 0);
        acc[mt][et] = __builtin_amdgcn_mfma_f32_16x16x32_bf16(Al[mt], bh, acc[mt][et], 0, 0, 0);
        acc[mt][et] = __builtin_amdgcn_mfma_f32_16x16x32_bf16(Ah[mt], bl, acc[mt][et], 0, 0, 0);
      }
    }
  }

  // epilogue: tanh -> v-dot -> E = exp(logit) (no max-sub; |logit| small)
  float E[2];
#pragma unroll
  for (int mt = 0; mt < 2; ++mt) {
    float ls[4] = {0.f, 0.f, 0.f, 0.f};
#pragma unroll
    for (int et = 0; et < 8; ++et) {
      float vv = av[col + 16 * et];
#pragma unroll
      for (int r = 0; r < 4; ++r) {
        float e2 = __builtin_amdgcn_exp2f(acc[mt][et][r] * C2L2E);
        float t = 1.0f - 2.0f * __builtin_amdgcn_rcpf(e2 + 1.0f);
        ls[r] += t * vv;
      }
    }
#pragma unroll
    for (int m = 1; m < 16; m <<= 1) {
      ls[0] += __shfl_xor(ls[0], m);
      ls[1] += __shfl_xor(ls[1], m);
      ls[2] += __shfl_xor(ls[2], m);
      ls[3] += __shfl_xor(ls[3], m);
    }
    float fl = (col == 0) ? ls[0] : (col == 1) ? ls[1] : (col == 2) ? ls[2] : ls[3];
    E[mt] = __builtin_amdgcn_exp2f(fl * L2E);
  }

  if (col < 4) {
    const int j = j0 + quad * 4 + col;
    float2 val = {E[0], E[1]};
    *(float2*)&Lg[((size_t)(b * 256 + j)) * 256 + i0 + 2 * w] = val;
    sRow[quad * 4 + col][w] = E[0] + E[1];
    if (ti != tj) {  // mirror (bitwise-identical by symmetry)
      Lg[((size_t)(b * 256 + i0 + 2 * w)) * 256 + j] = E[0];
      Lg[((size_t)(b * 256 + i0 + 2 * w + 1)) * 256 + j] = E[1];
    }
  }
  if (ti != tj) {  // mirror row sums: S[i] += sum over 16 j
#pragma unroll
    for (int mt = 0; mt < 2; ++mt) {
      float v = (col < 4) ? E[mt] : 0.f;
#pragma unroll
      for (int m = 1; m < 64; m <<= 1) v += __shfl_xor(v, m);
      if (lane == 0) sMir[2 * w + mt] = v;
    }
  }
  __syncthreads();
  if (tid < 16)
    atomicAdd(&S[b * 256 + j0 + tid],
              sRow[tid][0] + sRow[tid][1] + sRow[tid][2] + sRow[tid][3]);
  if (ti != tj && tid < 8) atomicAdd(&S[b * 256 + i0 + tid], sMir[tid]);
}

// ---------------- KB: agg (att=E/S, symmetric row reads) + h (fp64) + scores
__global__ void kB_aggh(const float* __restrict__ Lg, const float* __restrict__ S,
                        const float* __restrict__ x,
                        const float* __restrict__ pwa, const float* __restrict__ pwoa,
                        const float* __restrict__ pwab, const float* __restrict__ pwob,
                        const float* __restrict__ gam, const float* __restrict__ bet,
                        const float* __restrict__ mea, const float* __restrict__ varr,
                        const float* __restrict__ plw, const float* __restrict__ plb,
                        float* __restrict__ h, float* __restrict__ scores) {
  const int b = blockIdx.y, i0 = blockIdx.x * 8;
  const int tid = threadIdx.x;
  const int il = tid >> 5, dl = tid & 31;  // 8 i x 32 d-chunks
  __shared__ float sInv[256];
  __shared__ float satt[16][9];
  __shared__ float sxj[2048];
  __shared__ float sa[1024];
  __shared__ float sxi[1024];
  __shared__ double sScD[8][32];

  sInv[tid] = 1.0f / S[b * 256 + tid];
  ((float4*)sxi)[tid] = ((const float4*)(x + ((size_t)(b * 256 + i0)) * 128))[tid];

  float acc[4] = {0.f, 0.f, 0.f, 0.f};
  for (int jj = 0; jj < 256; jj += 16) {
    __syncthreads();
    if (tid < 128) {
      int ir = tid >> 4, jc = tid & 15;  // E(j,i)=E(i,j): coalesced row read
      satt[jc][ir] = Lg[((size_t)(b * 256 + i0 + ir)) * 256 + jj + jc] *
                     sInv[jj + jc];
    }
    const float4* xsrc = (const float4*)(x + ((size_t)(b * 256 + jj)) * 128);
    ((float4*)sxj)[tid] = xsrc[tid];
    ((float4*)sxj)[tid + 256] = xsrc[tid + 256];
    __syncthreads();
#pragma unroll
    for (int jl = 0; jl < 16; ++jl) {
      float a = satt[jl][il];
      float4 xv = *(const float4*)&sxj[jl * 128 + dl * 4];
      acc[0] += a * xv.x; acc[1] += a * xv.y;
      acc[2] += a * xv.z; acc[3] += a * xv.w;
    }
  }
  __syncthreads();
  *(float4*)&sa[il * 128 + dl * 4] = *(float4*)acc;
  __syncthreads();

  double z[4] = {0, 0, 0, 0};
  for (int k = 0; k < 128; ++k) {
    double a = (double)sa[il * 128 + k];
    float4 wv = *(const float4*)(pwa + k * 128 + dl * 4);
    z[0] += a * (double)wv.x; z[1] += a * (double)wv.y;
    z[2] += a * (double)wv.z; z[3] += a * (double)wv.w;
  }
  for (int k = 0; k < 128; ++k) {
    double a = (double)sxi[il * 128 + k];
    float4 wv = *(const float4*)(pwoa + k * 128 + dl * 4);
    z[0] += a * (double)wv.x; z[1] += a * (double)wv.y;
    z[2] += a * (double)wv.z; z[3] += a * (double)wv.w;
  }
  float o[4];
#pragma unroll
  for (int q = 0; q < 4; ++q) {
    int d = dl * 4 + q;
    double hv = z[q] + (double)pwab[d] + (double)pwob[d];
    double bn = (hv - (double)mea[d]) * (1.0 / sqrt((double)varr[d] + 1e-5)) *
                    (double)gam[d] +
                (double)bet[d];
    float bf = (float)bn;
    o[q] = bf > 0.f ? 1.0507009873554805f * bf
                    : 1.7580993408473766f *
                          (__builtin_amdgcn_exp2f(bf * L2E) - 1.0f);
  }
  *(float4*)(h + ((size_t)(b * 256 + i0 + il)) * 128 + dl * 4) = *(float4*)o;

  sScD[il][dl] = (double)o[0] * (double)plw[dl * 4] +
                 (double)o[1] * (double)plw[dl * 4 + 1] +
                 (double)o[2] * (double)plw[dl * 4 + 2] +
                 (double)o[3] * (double)plw[dl * 4 + 3];
  __syncthreads();
  if (tid < 8) {
    double zz = (double)plb[0];
    for (int c = 0; c < 32; ++c) zz += sScD[tid][c];
    scores[b * 256 + i0 + tid] = (float)(1.0 / (1.0 + exp(-zz)));
  }
}

// ---------------- KC: stable top-128 rank + gather h*score ------------------
__global__ __launch_bounds__(1024) void kC_topk(const float* __restrict__ h,
                                                const float* __restrict__ scores,
                                                float* __restrict__ out) {
  const int b = blockIdx.x, tid = threadIdx.x;
  const int t = tid >> 2, c = tid & 3;
  __shared__ float sc[256];
  __shared__ int ipart[256][4];
  __shared__ int sel[128];

  if (c == 0) sc[t] = scores[b * 256 + t];
  __syncthreads();
  {
    const float st = sc[t];
    int r = 0;
    for (int m = c * 64; m < c * 64 + 64; ++m) {
      float sm = sc[m];
      r += (sm > st) || (sm == st && m < t);  // stable descending
    }
    ipart[t][c] = r;
  }
  __syncthreads();
  if (c == 0) {
    int rank = ipart[t][0] + ipart[t][1] + ipart[t][2] + ipart[t][3];
    if (rank < 128) sel[rank] = t;
  }
  __syncthreads();
  const float4* h4 = (const float4*)(h + (size_t)b * 256 * 128);
  float4* o4 = (float4*)(out + (size_t)b * 128 * 128);
#pragma unroll
  for (int r = 0; r < 4; ++r) {
    int v = tid + 1024 * r;
    int row = v >> 5, q = v & 31;
    int src = sel[row];
    float ss = sc[src];
    float4 hv = h4[src * 32 + q];
    float4 ov;
    ov.x = hv.x * ss; ov.y = hv.y * ss; ov.z = hv.z * ss; ov.w = hv.w * ss;
    o4[row * 32 + q] = ov;
  }
}

extern "C" void kernel_launch(void* const* d_in, const int* in_sizes, int n_in,
                              void* d_out, int out_size, void* d_ws, size_t ws_size,
                              hipStream_t stream) {
  const float* x    = (const float*)d_in[0];
  const float* apw  = (const float*)d_in[1];
  const float* apb  = (const float*)d_in[2];
  const float* av   = (const float*)d_in[3];
  const float* pwa  = (const float*)d_in[4];
  const float* pwab = (const float*)d_in[5];
  const float* pwoa = (const float*)d_in[6];
  const float* pwob = (const float*)d_in[7];
  const float* gam  = (const float*)d_in[8];
  const float* bet  = (const float*)d_in[9];
  const float* mea  = (const float*)d_in[10];
  const float* varr = (const float*)d_in[11];
  const float* plw  = (const float*)d_in[12];
  const float* plb  = (const float*)d_in[13];
  float* out = (float*)d_out;

  // ws: gWhi 32K | gBlo 32K | S 16K | Lg 4M | h 2M | scores 16K
  unsigned short* gWhi = (unsigned short*)d_ws;
  unsigned short* gBlo = gWhi + 16384;
  float* S  = (float*)((char*)d_ws + 65536);
  float* Lg = (float*)((char*)d_ws + 81920);
  float* hb = Lg + (size_t)16 * 256 * 256;
  float* sco = hb + (size_t)16 * 256 * 128;

  k0_prep<<<144, 256, 0, stream>>>(apw, gWhi, gBlo, S);
  kA_logits<<<dim3(136, 2, 16), 256, 0, stream>>>(x, gWhi, gBlo, apb, av, Lg, S);
  kB_aggh<<<dim3(32, 16), 256, 0, stream>>>(Lg, S, x, pwa, pwoa, pwab, pwob,
                                            gam, bet, mea, varr, plw, plb, hb, sco);
  kC_topk<<<16, 1024, 0, stream>>>(hb, sco, out);
}